// Round 2
// baseline (140.910 us; speedup 1.0000x reference)
//
#include <hip/hip_runtime.h>
#include <hip/hip_bf16.h>

#define HW_N 9216
#define CH 256
#define NSPLIT 4
#define KEYS_PER_SPLIT (HW_N / NSPLIT)   // 2304
#define KBLK 64
#define PITCH 264                        // 256 + 8 bf16 pad -> 528B row stride, 2-way bank alias (free)
#define SCALE2 144.269504089f            // 100 / ln(2): exp(corr*100) = exp2(corr*SCALE2)

typedef __attribute__((ext_vector_type(8))) short bf16x8;
typedef __attribute__((ext_vector_type(4))) float f32x4;

__device__ inline unsigned short f2b(float f) {
    unsigned u = __builtin_bit_cast(unsigned, f);
    u += 0x7FFF + ((u >> 16) & 1);       // round-to-nearest-even
    return (unsigned short)(u >> 16);
}

// ---------------- kernel 1: per-channel partial sums (deterministic, no atomics) ----
__global__ void stats_partial(const float* __restrict__ x,
                              const float* __restrict__ y,
                              float* __restrict__ part) {
    int c = threadIdx.x;                  // 256 threads = 256 channels
    int r0 = blockIdx.x * 128;            // 72 blocks * 128 rows = 9216
    float xs = 0.f, xq = 0.f, ys = 0.f, yq = 0.f;
    for (int r = r0; r < r0 + 128; ++r) {
        float xv = x[(size_t)r * CH + c]; xs += xv; xq += xv * xv;
        float yv = y[(size_t)r * CH + c]; ys += yv; yq += yv * yv;
    }
    float* p = part + (size_t)blockIdx.x * 1024;
    p[c] = xs; p[256 + c] = xq; p[512 + c] = ys; p[768 + c] = yq;
}

// ---------------- kernel 2: finalize stats: mean and 1/L2norm per channel ----------
__global__ void stats_final(const float* __restrict__ part, float* __restrict__ stats) {
    int c = threadIdx.x;                  // 256 threads
    float xs = 0.f, xq = 0.f, ys = 0.f, yq = 0.f;
    for (int b = 0; b < 72; ++b) {
        const float* p = part + (size_t)b * 1024;
        xs += p[c]; xq += p[256 + c]; ys += p[512 + c]; yq += p[768 + c];
    }
    stats[c]       = xs / (float)HW_N;
    stats[256 + c] = 1.0f / sqrtf(xq);    // norm of ORIGINAL f (not centered)
    stats[512 + c] = ys / (float)HW_N;
    stats[768 + c] = 1.0f / sqrtf(yq);
}

// ---------------- kernel 3: normalize f32 -> bf16 xn / yn --------------------------
__global__ void normalize_k(const float* __restrict__ x,
                            const float* __restrict__ y,
                            const float* __restrict__ stats,
                            unsigned short* __restrict__ xn,
                            unsigned short* __restrict__ yn) {
    const float* src = blockIdx.y ? y : x;
    unsigned short* dst = blockIdx.y ? yn : xn;
    const float* st = stats + blockIdx.y * 512;
    int idx = (blockIdx.x * 256 + threadIdx.x) * 8;   // grid.x = 1152
    int c = idx & (CH - 1);
    float4 v0 = *(const float4*)(src + idx);
    float4 v1 = *(const float4*)(src + idx + 4);
    float f[8] = {v0.x, v0.y, v0.z, v0.w, v1.x, v1.y, v1.z, v1.w};
    bf16x8 o;
#pragma unroll
    for (int j = 0; j < 8; ++j)
        o[j] = (short)f2b((f[j] - st[c + j]) * st[256 + c + j]);
    *(bf16x8*)(dst + idx) = o;
}

// ---------------- kernel 4: fused corr -> online softmax -> PV + max ---------------
// grid (144, NSPLIT), block 256 (4 waves). Wave w owns q-rows [blk*64 + w*16, +16).
__launch_bounds__(256, 2)
__global__ void attn_k(const unsigned short* __restrict__ xn,
                       const unsigned short* __restrict__ yn,
                       const float* __restrict__ refimg,
                       float* __restrict__ part) {
    __shared__ short kt[KBLK * PITCH];
    int tid = threadIdx.x;
    int lane = tid & 63, wave = tid >> 6;
    int l15 = lane & 15, l16 = lane >> 4;
    int qb = blockIdx.x * 64 + wave * 16;

    // A fragments: q row = qb + (lane&15), k = kk*32 + (lane>>4)*8 + j
    bf16x8 a[8];
    const unsigned short* xrow = xn + (size_t)(qb + l15) * CH + l16 * 8;
#pragma unroll
    for (int kk = 0; kk < 8; ++kk) a[kk] = *(const bf16x8*)(xrow + kk * 32);

    float M[4], den[4], nA[4], nB[4];
#pragma unroll
    for (int i = 0; i < 4; ++i) { M[i] = -1e30f; den[i] = 0.f; nA[i] = 0.f; nB[i] = 0.f; }

    const float* refA = refimg + HW_N;       // ref[0,1,:,:]
    const float* refB = refimg + 2 * HW_N;   // ref[0,2,:,:]
    int key0 = blockIdx.y * KEYS_PER_SPLIT;

    for (int kb = key0; kb < key0 + KEYS_PER_SPLIT; kb += KBLK) {
        __syncthreads();
        // stage KBLK x 256 bf16 keys into LDS (padded rows)
#pragma unroll
        for (int i = 0; i < 8; ++i) {
            int flat = tid + 256 * i;                 // 0..2047
            int row = flat >> 5, ch8 = (flat & 31) * 8;
            *(bf16x8*)(kt + row * PITCH + ch8) =
                *(const bf16x8*)(yn + (size_t)(kb + row) * CH + ch8);
        }
        __syncthreads();

        f32x4 acc[4];
#pragma unroll
        for (int ct = 0; ct < 4; ++ct) acc[ct] = (f32x4){0.f, 0.f, 0.f, 0.f};
#pragma unroll
        for (int ct = 0; ct < 4; ++ct) {
            const short* bb = kt + (ct * 16 + l15) * PITCH + l16 * 8;
#pragma unroll
            for (int kk = 0; kk < 8; ++kk) {
                bf16x8 b = *(const bf16x8*)(bb + kk * 32);
                acc[ct] = __builtin_amdgcn_mfma_f32_16x16x32_bf16(a[kk], b, acc[ct], 0, 0, 0);
            }
        }
        // colors for this lane's 4 key columns
        float va[4], vb[4];
#pragma unroll
        for (int ct = 0; ct < 4; ++ct) {
            int key = kb + ct * 16 + l15;
            va[ct] = refA[key]; vb[ct] = refB[key];
        }
        // online softmax: acc[ct][i] = corr[q = qb + l16*4 + i][key = kb + ct*16 + l15]
#pragma unroll
        for (int i = 0; i < 4; ++i) {
            float t = fmaxf(fmaxf(acc[0][i], acc[1][i]), fmaxf(acc[2][i], acc[3][i]));
            t = fmaxf(t, __shfl_xor(t, 1, 64));
            t = fmaxf(t, __shfl_xor(t, 2, 64));
            t = fmaxf(t, __shfl_xor(t, 4, 64));
            t = fmaxf(t, __shfl_xor(t, 8, 64));
            float mn = fmaxf(M[i], t);
            float cs = exp2f((M[i] - mn) * SCALE2);
            den[i] *= cs; nA[i] *= cs; nB[i] *= cs; M[i] = mn;
#pragma unroll
            for (int ct = 0; ct < 4; ++ct) {
                float p = exp2f((acc[ct][i] - mn) * SCALE2);
                den[i] += p; nA[i] += p * va[ct]; nB[i] += p * vb[ct];
            }
        }
    }

    // reduce den/num across the 16 column-lanes of each row group
#pragma unroll
    for (int i = 0; i < 4; ++i) {
        den[i] += __shfl_xor(den[i], 1, 64); den[i] += __shfl_xor(den[i], 2, 64);
        den[i] += __shfl_xor(den[i], 4, 64); den[i] += __shfl_xor(den[i], 8, 64);
        nA[i]  += __shfl_xor(nA[i], 1, 64);  nA[i]  += __shfl_xor(nA[i], 2, 64);
        nA[i]  += __shfl_xor(nA[i], 4, 64);  nA[i]  += __shfl_xor(nA[i], 8, 64);
        nB[i]  += __shfl_xor(nB[i], 1, 64);  nB[i]  += __shfl_xor(nB[i], 2, 64);
        nB[i]  += __shfl_xor(nB[i], 4, 64);  nB[i]  += __shfl_xor(nB[i], 8, 64);
    }
    if (l15 == 0) {
#pragma unroll
        for (int i = 0; i < 4; ++i) {
            int q = qb + l16 * 4 + i;
            float* p = part + ((size_t)blockIdx.y * HW_N + q) * 4;
            p[0] = M[i]; p[1] = den[i]; p[2] = nA[i]; p[3] = nB[i];
        }
    }
}

// ---------------- kernel 5: merge splits, write f32 outputs ------------------------
__global__ void combine_k(const float* __restrict__ part, float* __restrict__ out) {
    int q = blockIdx.x * 256 + threadIdx.x;           // 36 blocks
    float M = -1e30f;
#pragma unroll
    for (int s = 0; s < NSPLIT; ++s) M = fmaxf(M, part[((size_t)s * HW_N + q) * 4]);
    float den = 0.f, nA = 0.f, nB = 0.f;
#pragma unroll
    for (int s = 0; s < NSPLIT; ++s) {
        const float* p = part + ((size_t)s * HW_N + q) * 4;
        float cs = exp2f((p[0] - M) * SCALE2);
        den += p[1] * cs; nA += p[2] * cs; nB += p[3] * cs;
    }
    out[q]            = nA / den;        // W channel a
    out[HW_N + q]     = nB / den;        // W channel b
    out[2 * HW_N + q] = M;               // confidence = max corr
}

extern "C" void kernel_launch(void* const* d_in, const int* in_sizes, int n_in,
                              void* d_out, int out_size, void* d_ws, size_t ws_size,
                              hipStream_t stream) {
    (void)in_sizes; (void)n_in; (void)out_size; (void)ws_size;
    const float* x   = (const float*)d_in[0];
    const float* y   = (const float*)d_in[1];
    const float* ref = (const float*)d_in[2];
    float* out = (float*)d_out;

    char* ws = (char*)d_ws;
    float* partA = (float*)ws;                                   // 72*1024*4   = 294912 B
    float* stats = (float*)(ws + 294912);                        // 1024*4      = 4096 B
    unsigned short* xn = (unsigned short*)(ws + 294912 + 4096);  // 9216*256*2  = 4718592 B
    unsigned short* yn = (unsigned short*)(ws + 294912 + 4096 + 4718592);
    float* partS = (float*)(ws + 294912 + 4096 + 2 * 4718592);   // 4*9216*4*4  = 589824 B

    hipLaunchKernelGGL(stats_partial, dim3(72), dim3(256), 0, stream, x, y, partA);
    hipLaunchKernelGGL(stats_final, dim3(1), dim3(256), 0, stream, partA, stats);
    hipLaunchKernelGGL(normalize_k, dim3(1152, 2), dim3(256), 0, stream, x, y, stats, xn, yn);
    hipLaunchKernelGGL(attn_k, dim3(144, NSPLIT), dim3(256), 0, stream, xn, yn, ref, partS);
    hipLaunchKernelGGL(combine_k, dim3(36), dim3(256), 0, stream, partS, out);
}

// Round 3
// 119.210 us; speedup vs baseline: 1.1820x; 1.1820x over previous
//
#include <hip/hip_runtime.h>
#include <hip/hip_bf16.h>

#define HW_N 9216
#define CH 256
#define NSPLIT 6
#define KEYS_PER_SPLIT (HW_N / NSPLIT)   // 1536 -> 24 tiles of 64
#define KBLK 64
#define PITCH 264                        // 256 + 8 bf16 pad; b128 reads are 2-way (minimum possible)
#define SCALE2 144.269504089f            // 100 / ln(2)

typedef __attribute__((ext_vector_type(8))) short bf16x8;
typedef __attribute__((ext_vector_type(4))) float f32x4;

__device__ inline unsigned short f2b(float f) {
    unsigned u = __builtin_bit_cast(unsigned, f);
    u += 0x7FFF + ((u >> 16) & 1);       // round-to-nearest-even
    return (unsigned short)(u >> 16);
}

// ---------------- kernel 1: per-channel partial sums (deterministic) ---------------
__global__ void stats_partial(const float* __restrict__ x,
                              const float* __restrict__ y,
                              float* __restrict__ part) {
    int c = threadIdx.x;                  // 256 threads = 256 channels
    int r0 = blockIdx.x * 128;            // 72 blocks * 128 rows = 9216
    float xs = 0.f, xq = 0.f, ys = 0.f, yq = 0.f;
    for (int r = r0; r < r0 + 128; ++r) {
        float xv = x[(size_t)r * CH + c]; xs += xv; xq += xv * xv;
        float yv = y[(size_t)r * CH + c]; ys += yv; yq += yv * yv;
    }
    float* p = part + (size_t)blockIdx.x * 1024;
    p[c] = xs; p[256 + c] = xq; p[512 + c] = ys; p[768 + c] = yq;
}

// ---------------- kernel 2: finalize stats ----------------------------------------
__global__ void stats_final(const float* __restrict__ part, float* __restrict__ stats) {
    int c = threadIdx.x;
    float xs = 0.f, xq = 0.f, ys = 0.f, yq = 0.f;
    for (int b = 0; b < 72; ++b) {
        const float* p = part + (size_t)b * 1024;
        xs += p[c]; xq += p[256 + c]; ys += p[512 + c]; yq += p[768 + c];
    }
    stats[c]       = xs / (float)HW_N;
    stats[256 + c] = 1.0f / sqrtf(xq);    // norm of ORIGINAL f (not centered)
    stats[512 + c] = ys / (float)HW_N;
    stats[768 + c] = 1.0f / sqrtf(yq);
}

// ---------------- kernel 3: normalize f32 -> bf16 ---------------------------------
__global__ void normalize_k(const float* __restrict__ x,
                            const float* __restrict__ y,
                            const float* __restrict__ stats,
                            unsigned short* __restrict__ xn,
                            unsigned short* __restrict__ yn) {
    const float* src = blockIdx.y ? y : x;
    unsigned short* dst = blockIdx.y ? yn : xn;
    const float* st = stats + blockIdx.y * 512;
    int idx = (blockIdx.x * 256 + threadIdx.x) * 8;   // grid.x = 1152
    int c = idx & (CH - 1);
    float4 v0 = *(const float4*)(src + idx);
    float4 v1 = *(const float4*)(src + idx + 4);
    float f[8] = {v0.x, v0.y, v0.z, v0.w, v1.x, v1.y, v1.z, v1.w};
    bf16x8 o;
#pragma unroll
    for (int j = 0; j < 8; ++j)
        o[j] = (short)f2b((f[j] - st[c + j]) * st[256 + c + j]);
    *(bf16x8*)(dst + idx) = o;
}

// ---------------- kernel 4: fused corr -> lane-local online softmax -> PV ----------
// grid (72, NSPLIT), block 256 (4 waves). Wave w owns 32 q-rows; 2 A-sets in regs.
__launch_bounds__(256, 2)
__global__ void attn_k(const unsigned short* __restrict__ xn,
                       const unsigned short* __restrict__ yn,
                       const float* __restrict__ refimg,
                       float* __restrict__ part) {
    __shared__ short kt[KBLK * PITCH];
    int tid = threadIdx.x;
    int lane = tid & 63, wave = tid >> 6;
    int l15 = lane & 15, l16 = lane >> 4;
    int qb = blockIdx.x * 128 + wave * 32;

    // A fragments for 2 q-sets: q = qb + qs*16 + (lane&15), k = kk*32 + (lane>>4)*8 + j
    bf16x8 a[2][8];
#pragma unroll
    for (int qs = 0; qs < 2; ++qs) {
        const unsigned short* xrow = xn + (size_t)(qb + qs * 16 + l15) * CH + l16 * 8;
#pragma unroll
        for (int kk = 0; kk < 8; ++kk) a[qs][kk] = *(const bf16x8*)(xrow + kk * 32);
    }

    // lane-local online softmax state (merged across 16 lanes at the end)
    float M[2][4], den[2][4], nA[2][4], nB[2][4];
#pragma unroll
    for (int qs = 0; qs < 2; ++qs)
#pragma unroll
        for (int i = 0; i < 4; ++i) {
            M[qs][i] = -1e30f; den[qs][i] = 0.f; nA[qs][i] = 0.f; nB[qs][i] = 0.f;
        }

    const float* refA = refimg + HW_N;       // ref[0,1,:,:]
    const float* refB = refimg + 2 * HW_N;   // ref[0,2,:,:]
    int key0 = blockIdx.y * KEYS_PER_SPLIT;

    for (int kb = key0; kb < key0 + KEYS_PER_SPLIT; kb += KBLK) {
        __syncthreads();
#pragma unroll
        for (int i = 0; i < 8; ++i) {
            int flat = tid + 256 * i;                 // 0..2047
            int row = flat >> 5, ch8 = (flat & 31) * 8;
            *(bf16x8*)(kt + row * PITCH + ch8) =
                *(const bf16x8*)(yn + (size_t)(kb + row) * CH + ch8);
        }
        __syncthreads();

        f32x4 acc0[4], acc1[4];
#pragma unroll
        for (int ct = 0; ct < 4; ++ct) {
            acc0[ct] = (f32x4){0.f, 0.f, 0.f, 0.f};
            acc1[ct] = (f32x4){0.f, 0.f, 0.f, 0.f};
        }
#pragma unroll
        for (int ct = 0; ct < 4; ++ct) {
            const short* bb = kt + (ct * 16 + l15) * PITCH + l16 * 8;
#pragma unroll
            for (int kk = 0; kk < 8; ++kk) {
                bf16x8 b = *(const bf16x8*)(bb + kk * 32);   // each B-frag feeds 2 MFMAs
                acc0[ct] = __builtin_amdgcn_mfma_f32_16x16x32_bf16(a[0][kk], b, acc0[ct], 0, 0, 0);
                acc1[ct] = __builtin_amdgcn_mfma_f32_16x16x32_bf16(a[1][kk], b, acc1[ct], 0, 0, 0);
            }
        }
        float va[4], vb[4];
#pragma unroll
        for (int ct = 0; ct < 4; ++ct) {
            int key = kb + ct * 16 + l15;
            va[ct] = refA[key]; vb[ct] = refB[key];
        }
        // acc[ct][i] = corr[q = qb + qs*16 + l16*4 + i][key = kb + ct*16 + l15]
#pragma unroll
        for (int qs = 0; qs < 2; ++qs)
#pragma unroll
            for (int i = 0; i < 4; ++i) {
                float c0 = qs ? acc1[0][i] : acc0[0][i];
                float c1 = qs ? acc1[1][i] : acc0[1][i];
                float c2 = qs ? acc1[2][i] : acc0[2][i];
                float c3 = qs ? acc1[3][i] : acc0[3][i];
                float t = fmaxf(fmaxf(c0, c1), fmaxf(c2, c3));
                if (t > M[qs][i]) {                  // defer-max: usually execz-skipped
                    float cs = exp2f((M[qs][i] - t) * SCALE2);
                    den[qs][i] *= cs; nA[qs][i] *= cs; nB[qs][i] *= cs; M[qs][i] = t;
                }
                float m = M[qs][i];
                float p0 = exp2f((c0 - m) * SCALE2);
                float p1 = exp2f((c1 - m) * SCALE2);
                float p2 = exp2f((c2 - m) * SCALE2);
                float p3 = exp2f((c3 - m) * SCALE2);
                den[qs][i] += (p0 + p1) + (p2 + p3);
                nA[qs][i] += p0 * va[0] + p1 * va[1] + p2 * va[2] + p3 * va[3];
                nB[qs][i] += p0 * vb[0] + p1 * vb[1] + p2 * vb[2] + p3 * vb[3];
            }
    }

    // merge lane-local states across the 16 column-lanes (same l16 group)
#pragma unroll
    for (int qs = 0; qs < 2; ++qs)
#pragma unroll
        for (int i = 0; i < 4; ++i) {
#pragma unroll
            for (int off = 1; off < 16; off <<= 1) {
                float Mo = __shfl_xor(M[qs][i], off, 64);
                float dn = __shfl_xor(den[qs][i], off, 64);
                float ao = __shfl_xor(nA[qs][i], off, 64);
                float bo = __shfl_xor(nB[qs][i], off, 64);
                float Mn = fmaxf(M[qs][i], Mo);
                float s0 = exp2f((M[qs][i] - Mn) * SCALE2);
                float s1 = exp2f((Mo - Mn) * SCALE2);
                den[qs][i] = den[qs][i] * s0 + dn * s1;
                nA[qs][i]  = nA[qs][i]  * s0 + ao * s1;
                nB[qs][i]  = nB[qs][i]  * s0 + bo * s1;
                M[qs][i] = Mn;
            }
        }
    if (l15 == 0) {
#pragma unroll
        for (int qs = 0; qs < 2; ++qs)
#pragma unroll
            for (int i = 0; i < 4; ++i) {
                int q = qb + qs * 16 + l16 * 4 + i;
                float* p = part + ((size_t)blockIdx.y * HW_N + q) * 4;
                p[0] = M[qs][i]; p[1] = den[qs][i]; p[2] = nA[qs][i]; p[3] = nB[qs][i];
            }
    }
}

// ---------------- kernel 5: merge splits, write f32 outputs ------------------------
__global__ void combine_k(const float* __restrict__ part, float* __restrict__ out) {
    int q = blockIdx.x * 256 + threadIdx.x;           // 36 blocks
    float M = -1e30f;
#pragma unroll
    for (int s = 0; s < NSPLIT; ++s) M = fmaxf(M, part[((size_t)s * HW_N + q) * 4]);
    float den = 0.f, nA = 0.f, nB = 0.f;
#pragma unroll
    for (int s = 0; s < NSPLIT; ++s) {
        const float* p = part + ((size_t)s * HW_N + q) * 4;
        float cs = exp2f((p[0] - M) * SCALE2);
        den += p[1] * cs; nA += p[2] * cs; nB += p[3] * cs;
    }
    out[q]            = nA / den;        // W channel a
    out[HW_N + q]     = nB / den;        // W channel b
    out[2 * HW_N + q] = M;               // confidence = max corr
}

extern "C" void kernel_launch(void* const* d_in, const int* in_sizes, int n_in,
                              void* d_out, int out_size, void* d_ws, size_t ws_size,
                              hipStream_t stream) {
    (void)in_sizes; (void)n_in; (void)out_size; (void)ws_size;
    const float* x   = (const float*)d_in[0];
    const float* y   = (const float*)d_in[1];
    const float* ref = (const float*)d_in[2];
    float* out = (float*)d_out;

    char* ws = (char*)d_ws;
    // xn/yn live for the whole pipeline; partA overlaps the (not-yet-written) xn
    // region since it is dead before normalize_k writes xn. stats sits after yn.
    unsigned short* xn = (unsigned short*)ws;                     // 4718592 B
    unsigned short* yn = (unsigned short*)(ws + 4718592);         // 4718592 B
    float* partA = (float*)ws;                                    // 72*1024*4 = 294912 B (dead before xn written)
    float* stats = (float*)(ws + 2 * 4718592);                    // 4096 B
    float* partS = (float*)(ws + 2 * 4718592 + 4096);             // 6*9216*4*4 = 884736 B
    // total: 10,326,016 B (same footprint as the previously-passing layout)

    hipLaunchKernelGGL(stats_partial, dim3(72), dim3(256), 0, stream, x, y, partA);
    hipLaunchKernelGGL(stats_final, dim3(1), dim3(256), 0, stream, partA, stats);
    hipLaunchKernelGGL(normalize_k, dim3(1152, 2), dim3(256), 0, stream, x, y, stats, xn, yn);
    hipLaunchKernelGGL(attn_k, dim3(72, NSPLIT), dim3(256), 0, stream, xn, yn, ref, partS);
    hipLaunchKernelGGL(combine_k, dim3(36), dim3(256), 0, stream, partS, out);
}